// Round 1
// baseline (3185.001 us; speedup 1.0000x reference)
//
#include <hip/hip_runtime.h>

#define N_USERS 100000
#define N_ITEMS 50000
#define N_NODES 150000
#define EMBED_DIM 64
#define N_EDGES 4800000
#define N_LAYERS 3

// Concatenate user_emb and item_emb into cur (layer buffer) and acc (output accumulator).
// float4-vectorized: total N_NODES*64/4 float4 elements.
__global__ void lgcn_init(const float* __restrict__ user_emb,
                          const float* __restrict__ item_emb,
                          float* __restrict__ cur,
                          float* __restrict__ acc) {
    int i = blockIdx.x * blockDim.x + threadIdx.x;
    const int total = N_NODES * EMBED_DIM / 4;
    if (i >= total) return;
    const int user_elems = N_USERS * EMBED_DIM / 4;
    float4 v;
    if (i < user_elems) {
        v = ((const float4*)user_emb)[i];
    } else {
        v = ((const float4*)item_emb)[i - user_elems];
    }
    ((float4*)cur)[i] = v;
    ((float4*)acc)[i] = v;
}

// One edge per 64-lane wave: lane d handles dim d.
// Coalesced 256B read of x[col], coalesced 64 atomicAdds into y[row].
__global__ void lgcn_spmm_atomic(const int* __restrict__ row,
                                 const int* __restrict__ col,
                                 const float* __restrict__ val,
                                 const float* __restrict__ x,
                                 float* __restrict__ y) {
    long long t = (long long)blockIdx.x * blockDim.x + threadIdx.x;
    int e = (int)(t >> 6);          // edge index (wave-uniform)
    int d = (int)(t & 63);          // dim (lane id)
    if (e >= N_EDGES) return;
    int r = row[e];
    int c = col[e];
    float v = val[e];
    float xv = x[(long long)c * EMBED_DIM + d];
    atomicAdd(&y[(long long)r * EMBED_DIM + d], v * xv);
}

// acc = (acc + cur) * s   (s = 1 for intermediate layers, 0.25 for the last)
__global__ void lgcn_accum(const float* __restrict__ cur,
                           float* __restrict__ acc,
                           float s) {
    int i = blockIdx.x * blockDim.x + threadIdx.x;
    const int total = N_NODES * EMBED_DIM / 4;
    if (i >= total) return;
    float4 a = ((const float4*)acc)[i];
    float4 c = ((const float4*)cur)[i];
    a.x = (a.x + c.x) * s;
    a.y = (a.y + c.y) * s;
    a.z = (a.z + c.z) * s;
    a.w = (a.w + c.w) * s;
    ((float4*)acc)[i] = a;
}

extern "C" void kernel_launch(void* const* d_in, const int* in_sizes, int n_in,
                              void* d_out, int out_size, void* d_ws, size_t ws_size,
                              hipStream_t stream) {
    const int*   adj_row  = (const int*)d_in[0];
    const int*   adj_col  = (const int*)d_in[1];
    const float* adj_val  = (const float*)d_in[2];
    const float* user_emb = (const float*)d_in[3];
    const float* item_emb = (const float*)d_in[4];
    float* acc = (float*)d_out;

    const size_t buf_elems = (size_t)N_NODES * EMBED_DIM;
    float* cur = (float*)d_ws;
    float* nxt = cur + buf_elems;

    // init: cur = emb, acc = emb
    {
        const int total = N_NODES * EMBED_DIM / 4;
        dim3 grid((total + 255) / 256), block(256);
        lgcn_init<<<grid, block, 0, stream>>>(user_emb, item_emb, cur, acc);
    }

    for (int layer = 0; layer < N_LAYERS; ++layer) {
        hipMemsetAsync(nxt, 0, buf_elems * sizeof(float), stream);

        {
            // one edge per wave, 64 lanes over dims
            long long total_threads = (long long)N_EDGES * 64;
            dim3 grid((unsigned)((total_threads + 255) / 256)), block(256);
            lgcn_spmm_atomic<<<grid, block, 0, stream>>>(adj_row, adj_col, adj_val, cur, nxt);
        }

        {
            float s = (layer == N_LAYERS - 1) ? (1.0f / (N_LAYERS + 1)) : 1.0f;
            const int total = N_NODES * EMBED_DIM / 4;
            dim3 grid((total + 255) / 256), block(256);
            lgcn_accum<<<grid, block, 0, stream>>>(nxt, acc, s);
        }

        // swap cur/nxt
        float* tmp = cur; cur = nxt; nxt = tmp;
    }
}

// Round 2
// 1472.360 us; speedup vs baseline: 2.1632x; 2.1632x over previous
//
#include <hip/hip_runtime.h>

#define N_USERS 100000
#define N_ITEMS 50000
#define N_NODES 150000
#define EMBED_DIM 64
#define N_EDGES 4800000
#define N_LAYERS 3

#define SCAN_BLK 1024
#define N_SCAN_BLOCKS ((N_NODES + SCAN_BLK - 1) / SCAN_BLK)

// ---------------- init: concat embeddings into cur and acc ----------------
__global__ void lgcn_init(const float* __restrict__ user_emb,
                          const float* __restrict__ item_emb,
                          float* __restrict__ cur,
                          float* __restrict__ acc) {
    int i = blockIdx.x * blockDim.x + threadIdx.x;
    const int total = N_NODES * EMBED_DIM / 4;
    if (i >= total) return;
    const int user_elems = N_USERS * EMBED_DIM / 4;
    float4 v;
    if (i < user_elems) v = ((const float4*)user_emb)[i];
    else                v = ((const float4*)item_emb)[i - user_elems];
    ((float4*)cur)[i] = v;
    ((float4*)acc)[i] = v;
}

// ---------------- CSR build ----------------
__global__ void k_hist(const int* __restrict__ row, int* __restrict__ counts) {
    int e = blockIdx.x * blockDim.x + threadIdx.x;
    if (e >= N_EDGES) return;
    atomicAdd(&counts[row[e]], 1);
}

// block-level exclusive scan (Hillis-Steele inclusive, then subtract self)
__global__ void k_scan1(const int* __restrict__ counts,
                        int* __restrict__ rowptr,
                        int* __restrict__ bsums) {
    __shared__ int sm[SCAN_BLK];
    int i = blockIdx.x * SCAN_BLK + threadIdx.x;
    int v = (i < N_NODES) ? counts[i] : 0;
    sm[threadIdx.x] = v;
    __syncthreads();
    for (int off = 1; off < SCAN_BLK; off <<= 1) {
        int t = (threadIdx.x >= off) ? sm[threadIdx.x - off] : 0;
        __syncthreads();
        sm[threadIdx.x] += t;
        __syncthreads();
    }
    if (i < N_NODES) rowptr[i] = sm[threadIdx.x] - v;   // exclusive
    if (threadIdx.x == SCAN_BLK - 1) bsums[blockIdx.x] = sm[SCAN_BLK - 1];
}

__global__ void k_scan2(int* __restrict__ bsums) {
    // tiny sequential scan over N_SCAN_BLOCKS (~147) entries
    if (blockIdx.x == 0 && threadIdx.x == 0) {
        int run = 0;
        for (int b = 0; b < N_SCAN_BLOCKS; ++b) {
            int t = bsums[b];
            bsums[b] = run;
            run += t;
        }
    }
}

__global__ void k_scan3(int* __restrict__ rowptr,
                        const int* __restrict__ bsums,
                        int* __restrict__ wr_off) {
    int i = blockIdx.x * blockDim.x + threadIdx.x;
    if (i < N_NODES) {
        int v = rowptr[i] + bsums[i >> 10];
        rowptr[i] = v;
        wr_off[i] = v;
    }
    if (i == 0) rowptr[N_NODES] = N_EDGES;
}

__global__ void k_scatter(const int* __restrict__ row,
                          const int* __restrict__ col,
                          const float* __restrict__ val,
                          int* __restrict__ wr_off,
                          int* __restrict__ csr_col,
                          float* __restrict__ csr_val) {
    int e = blockIdx.x * blockDim.x + threadIdx.x;
    if (e >= N_EDGES) return;
    int r = row[e];
    int p = atomicAdd(&wr_off[r], 1);
    csr_col[p] = col[e];
    csr_val[p] = val[e];
}

// ---------------- gather SpMV, fused with accumulation ----------------
// one wave per row; lane d owns dim d. rowptr/col/val loads are wave-uniform
// (scalarized via readfirstlane); x-gather is a coalesced 256B read (L3-hot).
__global__ void lgcn_spmv(const int* __restrict__ rowptr,
                          const int* __restrict__ csr_col,
                          const float* __restrict__ csr_val,
                          const float* __restrict__ x,
                          float* __restrict__ nxt,
                          float* __restrict__ acc,
                          float s, int write_nxt) {
    int t = blockIdx.x * blockDim.x + threadIdx.x;
    int wave = t >> 6;
    int lane = t & 63;
    if (wave >= N_NODES) return;
    int r = __builtin_amdgcn_readfirstlane(wave);
    int start = rowptr[r];
    int end   = rowptr[r + 1];
    float sum = 0.0f;
    for (int j = start; j < end; ++j) {
        int   c = csr_col[j];
        float v = csr_val[j];
        sum += v * x[(size_t)c * EMBED_DIM + lane];
    }
    size_t o = (size_t)r * EMBED_DIM + lane;
    if (write_nxt) nxt[o] = sum;
    acc[o] = (acc[o] + sum) * s;
}

// ---------------- round-1 fallback (atomic scatter) ----------------
__global__ void lgcn_spmm_atomic(const int* __restrict__ row,
                                 const int* __restrict__ col,
                                 const float* __restrict__ val,
                                 const float* __restrict__ x,
                                 float* __restrict__ y) {
    long long t = (long long)blockIdx.x * blockDim.x + threadIdx.x;
    int e = (int)(t >> 6);
    int d = (int)(t & 63);
    if (e >= N_EDGES) return;
    int r = row[e];
    int c = col[e];
    float v = val[e];
    atomicAdd(&y[(long long)r * EMBED_DIM + d], v * x[(long long)c * EMBED_DIM + d]);
}

__global__ void lgcn_accum(const float* __restrict__ cur,
                           float* __restrict__ acc, float s) {
    int i = blockIdx.x * blockDim.x + threadIdx.x;
    const int total = N_NODES * EMBED_DIM / 4;
    if (i >= total) return;
    float4 a = ((const float4*)acc)[i];
    float4 c = ((const float4*)cur)[i];
    a.x = (a.x + c.x) * s; a.y = (a.y + c.y) * s;
    a.z = (a.z + c.z) * s; a.w = (a.w + c.w) * s;
    ((float4*)acc)[i] = a;
}

extern "C" void kernel_launch(void* const* d_in, const int* in_sizes, int n_in,
                              void* d_out, int out_size, void* d_ws, size_t ws_size,
                              hipStream_t stream) {
    const int*   adj_row  = (const int*)d_in[0];
    const int*   adj_col  = (const int*)d_in[1];
    const float* adj_val  = (const float*)d_in[2];
    const float* user_emb = (const float*)d_in[3];
    const float* item_emb = (const float*)d_in[4];
    float* acc = (float*)d_out;

    const size_t buf_elems = (size_t)N_NODES * EMBED_DIM;

    // workspace layout
    char* wp = (char*)d_ws;
    float* cur = (float*)wp;                 wp += buf_elems * sizeof(float);
    float* nxt = (float*)wp;                 wp += buf_elems * sizeof(float);
    int*   rowptr = (int*)wp;                wp += (N_NODES + 1) * sizeof(int);
    int*   wr_off = (int*)wp;                wp += N_NODES * sizeof(int);
    int*   bsums  = (int*)wp;                wp += N_SCAN_BLOCKS * sizeof(int);
    // align to 16
    wp = (char*)(((size_t)wp + 15) & ~(size_t)15);
    int*   csr_col = (int*)wp;               wp += (size_t)N_EDGES * sizeof(int);
    float* csr_val = (float*)wp;             wp += (size_t)N_EDGES * sizeof(float);
    size_t needed = (size_t)(wp - (char*)d_ws);

    // init cur/acc
    {
        const int total = N_NODES * EMBED_DIM / 4;
        lgcn_init<<<(total + 255) / 256, 256, 0, stream>>>(user_emb, item_emb, cur, acc);
    }

    if (needed <= ws_size) {
        // ---- CSR build ----
        hipMemsetAsync(wr_off, 0, N_NODES * sizeof(int), stream);  // reuse wr_off as counts
        k_hist<<<(N_EDGES + 255) / 256, 256, 0, stream>>>(adj_row, wr_off);
        k_scan1<<<N_SCAN_BLOCKS, SCAN_BLK, 0, stream>>>(wr_off, rowptr, bsums);
        k_scan2<<<1, 1, 0, stream>>>(bsums);
        k_scan3<<<(N_NODES + 255) / 256, 256, 0, stream>>>(rowptr, bsums, wr_off);
        k_scatter<<<(N_EDGES + 255) / 256, 256, 0, stream>>>(adj_row, adj_col, adj_val,
                                                             wr_off, csr_col, csr_val);

        // ---- 3 fused SpMV + accumulate layers ----
        const long long tthreads = (long long)N_NODES * 64;
        const int nblk = (int)((tthreads + 255) / 256);
        float* a = cur; float* b = nxt;
        for (int layer = 0; layer < N_LAYERS; ++layer) {
            float s = (layer == N_LAYERS - 1) ? (1.0f / (N_LAYERS + 1)) : 1.0f;
            int write_nxt = (layer != N_LAYERS - 1);
            lgcn_spmv<<<nblk, 256, 0, stream>>>(rowptr, csr_col, csr_val, a, b, acc, s, write_nxt);
            float* tmp = a; a = b; b = tmp;
        }
    } else {
        // ---- fallback: round-1 atomic path ----
        float* a = cur; float* b = nxt;
        for (int layer = 0; layer < N_LAYERS; ++layer) {
            hipMemsetAsync(b, 0, buf_elems * sizeof(float), stream);
            long long total_threads = (long long)N_EDGES * 64;
            lgcn_spmm_atomic<<<(unsigned)((total_threads + 255) / 256), 256, 0, stream>>>(
                adj_row, adj_col, adj_val, a, b);
            float s = (layer == N_LAYERS - 1) ? (1.0f / (N_LAYERS + 1)) : 1.0f;
            const int total = N_NODES * EMBED_DIM / 4;
            lgcn_accum<<<(total + 255) / 256, 256, 0, stream>>>(b, acc, s);
            float* tmp = a; a = b; b = tmp;
        }
    }
}

// Round 3
// 1279.158 us; speedup vs baseline: 2.4899x; 1.1510x over previous
//
#include <hip/hip_runtime.h>

#define N_USERS 100000
#define N_ITEMS 50000
#define N_NODES 150000
#define EMBED_DIM 64
#define N_EDGES 4800000
#define N_LAYERS 3

#define SCAN_BLK 1024
#define N_SCAN_BLOCKS ((N_NODES + SCAN_BLK - 1) / SCAN_BLK)

#define BKT_SHIFT 10
#define N_BKT ((N_NODES + (1 << BKT_SHIFT) - 1) >> BKT_SHIFT)   // 147
#define EPB 8192   // edges per block in partition kernels

// ---------------- init: concat embeddings into cur and acc ----------------
__global__ void lgcn_init(const float* __restrict__ user_emb,
                          const float* __restrict__ item_emb,
                          float* __restrict__ cur,
                          float* __restrict__ acc) {
    int i = blockIdx.x * blockDim.x + threadIdx.x;
    const int total = N_NODES * EMBED_DIM / 4;
    if (i >= total) return;
    const int user_elems = N_USERS * EMBED_DIM / 4;
    float4 v;
    if (i < user_elems) v = ((const float4*)user_emb)[i];
    else                v = ((const float4*)item_emb)[i - user_elems];
    ((float4*)cur)[i] = v;
    ((float4*)acc)[i] = v;
}

// ---------------- CSR build ----------------
__global__ void k_hist(const int* __restrict__ row, int* __restrict__ counts) {
    int e = blockIdx.x * blockDim.x + threadIdx.x;
    if (e >= N_EDGES) return;
    atomicAdd(&counts[row[e]], 1);
}

__global__ void k_scan1(const int* __restrict__ counts,
                        int* __restrict__ rowptr,
                        int* __restrict__ bsums) {
    __shared__ int sm[SCAN_BLK];
    int i = blockIdx.x * SCAN_BLK + threadIdx.x;
    int v = (i < N_NODES) ? counts[i] : 0;
    sm[threadIdx.x] = v;
    __syncthreads();
    for (int off = 1; off < SCAN_BLK; off <<= 1) {
        int t = (threadIdx.x >= off) ? sm[threadIdx.x - off] : 0;
        __syncthreads();
        sm[threadIdx.x] += t;
        __syncthreads();
    }
    if (i < N_NODES) rowptr[i] = sm[threadIdx.x] - v;   // exclusive
    if (threadIdx.x == SCAN_BLK - 1) bsums[blockIdx.x] = sm[SCAN_BLK - 1];
}

__global__ void k_scan2(int* __restrict__ bsums) {
    if (blockIdx.x == 0 && threadIdx.x == 0) {
        int run = 0;
        for (int b = 0; b < N_SCAN_BLOCKS; ++b) {
            int t = bsums[b];
            bsums[b] = run;
            run += t;
        }
    }
}

__global__ void k_scan3(int* __restrict__ rowptr,
                        const int* __restrict__ bsums,
                        int* __restrict__ wr_off) {
    int i = blockIdx.x * blockDim.x + threadIdx.x;
    if (i < N_NODES) {
        int v = rowptr[i] + bsums[i >> 10];
        rowptr[i] = v;
        wr_off[i] = v;
    }
    if (i == 0) rowptr[N_NODES] = N_EDGES;
}

// bucket base offsets = rowptr at each bucket's first row
__global__ void k_bktbase(const int* __restrict__ rowptr, int* __restrict__ bkt_cnt) {
    int i = threadIdx.x;
    for (; i < N_BKT; i += blockDim.x)
        bkt_cnt[i] = rowptr[i << BKT_SHIFT];
}

// pass 1: partition edges into N_BKT row-buckets (append, line-friendly)
__global__ __launch_bounds__(256)
void k_part1(const int* __restrict__ row,
             const int* __restrict__ col,
             const int* __restrict__ valI,
             int* __restrict__ bkt_cnt,
             int* __restrict__ tmp_r,
             int2* __restrict__ tmp_cv) {
    __shared__ int h[N_BKT];
    __shared__ int off[N_BKT];
    int e0 = blockIdx.x * EPB;
    int e1 = e0 + EPB; if (e1 > N_EDGES) e1 = N_EDGES;
    for (int i = threadIdx.x; i < N_BKT; i += 256) h[i] = 0;
    __syncthreads();
    for (int e = e0 + threadIdx.x; e < e1; e += 256)
        atomicAdd(&h[row[e] >> BKT_SHIFT], 1);
    __syncthreads();
    for (int i = threadIdx.x; i < N_BKT; i += 256)
        off[i] = atomicAdd(&bkt_cnt[i], h[i]);
    __syncthreads();
    for (int e = e0 + threadIdx.x; e < e1; e += 256) {
        int r = row[e];
        int b = r >> BKT_SHIFT;
        int p = atomicAdd(&off[b], 1);
        tmp_r[p]  = r;
        tmp_cv[p] = make_int2(col[e], valI[e]);
    }
}

// pass 2: fine scatter within buckets (targets are L2-local ~256KB regions)
__global__ __launch_bounds__(256)
void k_part2(const int* __restrict__ tmp_r,
             const int2* __restrict__ tmp_cv,
             int* __restrict__ wr_off,
             int2* __restrict__ csr_cv) {
    int e0 = blockIdx.x * EPB;
    int e1 = e0 + EPB; if (e1 > N_EDGES) e1 = N_EDGES;
    for (int e = e0 + threadIdx.x; e < e1; e += 256) {
        int r = tmp_r[e];
        int p = atomicAdd(&wr_off[r], 1);
        csr_cv[p] = tmp_cv[e];
    }
}

// ---------------- gather SpMV, fused with accumulation ----------------
__global__ __launch_bounds__(256)
void lgcn_spmv(const int* __restrict__ rowptr,
               const int2* __restrict__ cv,
               const float* __restrict__ x,
               float* __restrict__ nxt,
               float* __restrict__ acc,
               float s, int write_nxt) {
    int t = blockIdx.x * blockDim.x + threadIdx.x;
    int wave = t >> 6;
    int lane = t & 63;
    if (wave >= N_NODES) return;
    int r = __builtin_amdgcn_readfirstlane(wave);
    int start = rowptr[r];
    int end   = rowptr[r + 1];
    float s0 = 0.f, s1 = 0.f, s2 = 0.f, s3 = 0.f;
    int j = start;
    for (; j + 4 <= end; j += 4) {
        int2 a0 = cv[j], a1 = cv[j + 1], a2 = cv[j + 2], a3 = cv[j + 3];
        s0 += __int_as_float(a0.y) * x[((size_t)a0.x << 6) + lane];
        s1 += __int_as_float(a1.y) * x[((size_t)a1.x << 6) + lane];
        s2 += __int_as_float(a2.y) * x[((size_t)a2.x << 6) + lane];
        s3 += __int_as_float(a3.y) * x[((size_t)a3.x << 6) + lane];
    }
    for (; j < end; ++j) {
        int2 a = cv[j];
        s0 += __int_as_float(a.y) * x[((size_t)a.x << 6) + lane];
    }
    float sum = (s0 + s1) + (s2 + s3);
    size_t o = ((size_t)r << 6) + lane;
    if (write_nxt) nxt[o] = sum;
    acc[o] = (acc[o] + sum) * s;
}

// ---------------- fallback (atomic scatter) ----------------
__global__ void lgcn_spmm_atomic(const int* __restrict__ row,
                                 const int* __restrict__ col,
                                 const float* __restrict__ val,
                                 const float* __restrict__ x,
                                 float* __restrict__ y) {
    long long t = (long long)blockIdx.x * blockDim.x + threadIdx.x;
    int e = (int)(t >> 6);
    int d = (int)(t & 63);
    if (e >= N_EDGES) return;
    int r = row[e];
    int c = col[e];
    float v = val[e];
    atomicAdd(&y[(long long)r * EMBED_DIM + d], v * x[(long long)c * EMBED_DIM + d]);
}

__global__ void lgcn_accum(const float* __restrict__ cur,
                           float* __restrict__ acc, float s) {
    int i = blockIdx.x * blockDim.x + threadIdx.x;
    const int total = N_NODES * EMBED_DIM / 4;
    if (i >= total) return;
    float4 a = ((const float4*)acc)[i];
    float4 c = ((const float4*)cur)[i];
    a.x = (a.x + c.x) * s; a.y = (a.y + c.y) * s;
    a.z = (a.z + c.z) * s; a.w = (a.w + c.w) * s;
    ((float4*)acc)[i] = a;
}

extern "C" void kernel_launch(void* const* d_in, const int* in_sizes, int n_in,
                              void* d_out, int out_size, void* d_ws, size_t ws_size,
                              hipStream_t stream) {
    const int*   adj_row  = (const int*)d_in[0];
    const int*   adj_col  = (const int*)d_in[1];
    const float* adj_val  = (const float*)d_in[2];
    const int*   adj_valI = (const int*)d_in[2];
    const float* user_emb = (const float*)d_in[3];
    const float* item_emb = (const float*)d_in[4];
    float* acc = (float*)d_out;

    const size_t buf_elems = (size_t)N_NODES * EMBED_DIM;

    // ---- workspace layout ----
    char* wp = (char*)d_ws;
    int*  rowptr  = (int*)wp;  wp += (size_t)(N_NODES + 1) * sizeof(int);
    int*  wr_off  = (int*)wp;  wp += (size_t)N_NODES * sizeof(int);
    int*  bsums   = (int*)wp;  wp += (size_t)N_SCAN_BLOCKS * sizeof(int);
    int*  bkt_cnt = (int*)wp;  wp += (size_t)N_BKT * sizeof(int);
    wp = (char*)(((size_t)wp + 15) & ~(size_t)15);
    int2* csr_cv  = (int2*)wp; wp += (size_t)N_EDGES * sizeof(int2);
    wp = (char*)(((size_t)wp + 15) & ~(size_t)15);
    // union region: {cur, nxt} during SpMV  <->  {tmp_cv, tmp_r} during build
    char* uni = wp;
    float* cur = (float*)uni;
    float* nxt = cur + buf_elems;
    int2*  tmp_cv = (int2*)uni;
    int*   tmp_r  = (int*)(uni + (size_t)N_EDGES * sizeof(int2));
    size_t uni_bytes = 2 * buf_elems * sizeof(float);               // 76.8MB >= 57.6MB tmp
    size_t needed = (size_t)(uni - (char*)d_ws) + uni_bytes;

    if (needed <= ws_size) {
        // ---- CSR build (before init; tmp aliases cur/nxt) ----
        hipMemsetAsync(wr_off, 0, N_NODES * sizeof(int), stream);   // counts
        k_hist<<<(N_EDGES + 255) / 256, 256, 0, stream>>>(adj_row, wr_off);
        k_scan1<<<N_SCAN_BLOCKS, SCAN_BLK, 0, stream>>>(wr_off, rowptr, bsums);
        k_scan2<<<1, 1, 0, stream>>>(bsums);
        k_scan3<<<(N_NODES + 255) / 256, 256, 0, stream>>>(rowptr, bsums, wr_off);
        k_bktbase<<<1, 256, 0, stream>>>(rowptr, bkt_cnt);
        const int nblk_p = (N_EDGES + EPB - 1) / EPB;
        k_part1<<<nblk_p, 256, 0, stream>>>(adj_row, adj_col, adj_valI,
                                            bkt_cnt, tmp_r, tmp_cv);
        k_part2<<<nblk_p, 256, 0, stream>>>(tmp_r, tmp_cv, wr_off, csr_cv);

        // ---- init cur/acc (overwrites tmp region — tmp is dead now) ----
        {
            const int total = N_NODES * EMBED_DIM / 4;
            lgcn_init<<<(total + 255) / 256, 256, 0, stream>>>(user_emb, item_emb, cur, acc);
        }

        // ---- 3 fused SpMV + accumulate layers ----
        const long long tthreads = (long long)N_NODES * 64;
        const int nblk = (int)((tthreads + 255) / 256);
        float* a = cur; float* b = nxt;
        for (int layer = 0; layer < N_LAYERS; ++layer) {
            float s = (layer == N_LAYERS - 1) ? (1.0f / (N_LAYERS + 1)) : 1.0f;
            int write_nxt = (layer != N_LAYERS - 1);
            lgcn_spmv<<<nblk, 256, 0, stream>>>(rowptr, csr_cv, a, b, acc, s, write_nxt);
            float* tmp = a; a = b; b = tmp;
        }
    } else {
        // ---- fallback: atomic path ----
        float* curF = (float*)d_ws;
        float* nxtF = curF + buf_elems;
        const int total = N_NODES * EMBED_DIM / 4;
        lgcn_init<<<(total + 255) / 256, 256, 0, stream>>>(user_emb, item_emb, curF, acc);
        float* a = curF; float* b = nxtF;
        for (int layer = 0; layer < N_LAYERS; ++layer) {
            hipMemsetAsync(b, 0, buf_elems * sizeof(float), stream);
            long long total_threads = (long long)N_EDGES * 64;
            lgcn_spmm_atomic<<<(unsigned)((total_threads + 255) / 256), 256, 0, stream>>>(
                adj_row, adj_col, adj_val, a, b);
            float s = (layer == N_LAYERS - 1) ? (1.0f / (N_LAYERS + 1)) : 1.0f;
            lgcn_accum<<<(total + 255) / 256, 256, 0, stream>>>(b, acc, s);
            float* tmp = a; a = b; b = tmp;
        }
    }
}